// Round 2
// baseline (375.499 us; speedup 1.0000x reference)
//
#include <hip/hip_runtime.h>

// B=4, S=2048, D=1024, H=16, Dk=64.  M = B*S = 8192.
// cvt(fp32->bf16) -> proj GEMMs (256^2-tile, BK=32, depth-3 counted-vmcnt
// pipeline, ONE barrier per K-tile, phase-ahead ds_read prefetch; q/k
// [bh][s][dk], v^T sigma-permuted [bh][dk][s], q pre-scaled 0.125*log2e)
// -> flash attn v3 (S^T 32x32x16, P-in-regs via sigma trick, 64 q/wave)
// -> out GEMM (m97 128^2 core).  Workspace: 104 MB.
//
// proj_gemm v3 schedule (per K-tile T, steady state):
//   P1: issue GLD A(T+3); ds_read afB <- T.phase2 A-frags; 16 MFMA (afA,bg)
//   P2: issue GLD B(T+3); ds_read afA <- (T+1).P1 A-frags + bg' <- (T+1);
//       16 MFMA (afB,bg); vmcnt(4) [T+2 landed]; s_barrier
// Fragments for a phase are always read one phase earlier, so MFMA overlaps
// ds_read latency; compiler inserts the counted lgkmcnt before each use.
// LDS XOR-chunk swizzle both-sides (pre-swizzled global src for linear
// global_load_lds dest, same XOR on ds_read) -> 0 bank conflicts (verified r1).

typedef __bf16 bhalf_t;
typedef __attribute__((ext_vector_type(8)))  __bf16 bf16x8;
typedef __attribute__((ext_vector_type(4)))  __bf16 bf16x4;
typedef __attribute__((ext_vector_type(4)))  float  f32x4;
typedef __attribute__((ext_vector_type(16))) float  f32x16;

typedef __attribute__((address_space(1))) void gvoid_t;
typedef __attribute__((address_space(3))) void lvoid_t;
#define GLD16(g, l) __builtin_amdgcn_global_load_lds((const gvoid_t*)(g), (lvoid_t*)(l), 16, 0, 0)

#define SB0()   __builtin_amdgcn_sched_barrier(0)
#define BARX()  asm volatile("s_barrier" ::: "memory")
#define VMW(n)  asm volatile("s_waitcnt vmcnt(" #n ")" ::: "memory")

// ---------------------------------------------------------------------------
__global__ __launch_bounds__(256) void cvt_all(
    const float* __restrict__ Q, const float* __restrict__ Kin, const float* __restrict__ V,
    const float* __restrict__ Wq, const float* __restrict__ Wk, const float* __restrict__ Wv,
    const float* __restrict__ Wo,
    bhalf_t* __restrict__ Qb, bhalf_t* __restrict__ Kb, bhalf_t* __restrict__ Vb,
    bhalf_t* __restrict__ Wqb, bhalf_t* __restrict__ Wkb, bhalf_t* __restrict__ Wvb,
    bhalf_t* __restrict__ Wob)
{
  size_t t = (size_t)blockIdx.x * 256 + threadIdx.x;   // float4 index
  const float* src; bhalf_t* dst;
  if (t < 2097152)      { src = Q;   dst = Qb; }
  else if (t < 4194304) { src = Kin; dst = Kb; t -= 2097152; }
  else if (t < 6291456) { src = V;   dst = Vb; t -= 4194304; }
  else {
    t -= 6291456;
    int w = (int)(t >> 18); t &= 262143;
    src = (w == 0) ? Wq  : (w == 1) ? Wk  : (w == 2) ? Wv  : Wo;
    dst = (w == 0) ? Wqb : (w == 1) ? Wkb : (w == 2) ? Wvb : Wob;
  }
  float4 f = ((const float4*)src)[t];
  bf16x4 o;
  o.x = (bhalf_t)f.x; o.y = (bhalf_t)f.y; o.z = (bhalf_t)f.z; o.w = (bhalf_t)f.w;
  ((bf16x4*)dst)[t] = o;
}

// ---------------------------------------------------------------------------
// m97-style GEMM core (kept for out_gemm): C[128x128] of A[M,1024] @ B^T
// ---------------------------------------------------------------------------
__device__ __forceinline__ void gemm_core_128(
    const bhalf_t* __restrict__ A, const bhalf_t* __restrict__ B,
    int bm, int bn, bhalf_t* As, bhalf_t* Bs, f32x4 acc[4][4])
{
  const int tid = threadIdx.x, lane = tid & 63, wave = tid >> 6;
  const int wm = wave >> 1, wn = wave & 1;
  const int quad = lane >> 4, tn = lane & 15;
  const int srow = lane >> 2, scol = (lane & 3) * 8;

  const bhalf_t* Ab0 = A + (size_t)(bm * 128 + wave * 16 + srow) * 1024 + scol;
  const bhalf_t* Ab1 = Ab0 + (size_t)64 * 1024;
  const bhalf_t* Bb0 = B + (size_t)(bn * 128 + wave * 16 + srow) * 1024 + scol;
  const bhalf_t* Bb1 = Bb0 + (size_t)64 * 1024;
  bhalf_t* Asw0 = As + wave * 512;  bhalf_t* Asw1 = As + (wave + 4) * 512;
  bhalf_t* Bsw0 = Bs + wave * 512;  bhalf_t* Bsw1 = Bs + (wave + 4) * 512;

  for (int k0 = 0; k0 < 1024; k0 += 32) {
    GLD16(Ab0 + k0, Asw0);
    GLD16(Ab1 + k0, Asw1);
    GLD16(Bb0 + k0, Bsw0);
    GLD16(Bb1 + k0, Bsw1);
    __syncthreads();
    bf16x8 af[4], bfr[4];
#pragma unroll
    for (int i = 0; i < 4; ++i)
      af[i] = *(const bf16x8*)(As + (wm * 64 + i * 16 + tn) * 32 + quad * 8);
#pragma unroll
    for (int j = 0; j < 4; ++j)
      bfr[j] = *(const bf16x8*)(Bs + (wn * 64 + j * 16 + tn) * 32 + quad * 8);
#pragma unroll
    for (int i = 0; i < 4; ++i)
#pragma unroll
      for (int j = 0; j < 4; ++j)
        acc[i][j] = __builtin_amdgcn_mfma_f32_16x16x32_bf16(af[i], bfr[j], acc[i][j], 0, 0, 0);
    __syncthreads();
  }
}

// ---------------------------------------------------------------------------
// proj_gemm v3: 256x256 tile, BK=32, depth-3 prefetch, 1 barrier/K-tile,
// phase-ahead fragment reads (ping-pong regs afA/afB, bg0/bg1).
// ---------------------------------------------------------------------------
#define PH1(T, BG, ISSUE)                                                      \
  {                                                                            \
    if (ISSUE) {                                                               \
      bhalf_t* And = As + (((T) + 3) & 3) * 8192;                              \
      GLD16(Asrc0 + ((T) + 3) * 32, And + w * 512);                            \
      GLD16(Asrc1 + ((T) + 3) * 32, And + (w + 8) * 512);                      \
    }                                                                          \
    {                                                                          \
      bhalf_t* AsB = As + ((T) & 3) * 8192;                                    \
      _Pragma("unroll")                                                        \
      for (int i = 0; i < 4; ++i)                                              \
        afB[i] = *(const bf16x8*)(AsB + arow + (i + 4) * 1024 + aswz);         \
    }                                                                          \
    SB0();                                                                     \
    __builtin_amdgcn_s_setprio(1);                                             \
    _Pragma("unroll")                                                          \
    for (int i = 0; i < 4; ++i)                                                \
      _Pragma("unroll")                                                        \
      for (int j = 0; j < 4; ++j)                                              \
        acc[i][j] = __builtin_amdgcn_mfma_f32_16x16x32_bf16(afA[i], BG[j], acc[i][j], 0, 0, 0); \
    __builtin_amdgcn_s_setprio(0);                                             \
    SB0();                                                                     \
  }

#define PH2(T, BG, BGN, ISSUE, PRIME, GATE, DOBAR)                             \
  {                                                                            \
    if (ISSUE) {                                                               \
      bhalf_t* Bnd = Bs + (((T) + 3) & 3) * 8192;                              \
      GLD16(Bsrc0 + ((T) + 3) * 32, Bnd + w * 512);                            \
      GLD16(Bsrc1 + ((T) + 3) * 32, Bnd + (w + 8) * 512);                      \
    }                                                                          \
    if (PRIME) {                                                               \
      bhalf_t* AsN = As + (((T) + 1) & 3) * 8192;                              \
      bhalf_t* BsN = Bs + (((T) + 1) & 3) * 8192;                              \
      _Pragma("unroll")                                                        \
      for (int i = 0; i < 4; ++i)                                              \
        afA[i] = *(const bf16x8*)(AsN + arow + i * 1024 + aswz);               \
      _Pragma("unroll")                                                        \
      for (int j = 0; j < 4; ++j)                                              \
        BGN[j] = *(const bf16x8*)(BsN + brow + j * 1024 + bswz);               \
    }                                                                          \
    SB0();                                                                     \
    __builtin_amdgcn_s_setprio(1);                                             \
    _Pragma("unroll")                                                          \
    for (int i = 0; i < 4; ++i)                                                \
      _Pragma("unroll")                                                        \
      for (int j = 0; j < 4; ++j)                                              \
        acc[i + 4][j] = __builtin_amdgcn_mfma_f32_16x16x32_bf16(afB[i], BG[j], acc[i + 4][j], 0, 0, 0); \
    __builtin_amdgcn_s_setprio(0);                                             \
    SB0();                                                                     \
    GATE;                                                                      \
    if (DOBAR) BARX();                                                         \
  }

__global__ __launch_bounds__(512, 2) void proj_gemm(
    const bhalf_t* __restrict__ Qb, const bhalf_t* __restrict__ Kb, const bhalf_t* __restrict__ Vb,
    const bhalf_t* __restrict__ Wqb, const bhalf_t* __restrict__ Wkb, const bhalf_t* __restrict__ Wvb,
    const float* __restrict__ bq, const float* __restrict__ bk, const float* __restrict__ bv,
    bhalf_t* __restrict__ qo, bhalf_t* __restrict__ ko, bhalf_t* __restrict__ vto)
{
  __shared__ bhalf_t As[4 * 8192];   // 4 bufs x [128][64] bf16 (row-paired)
  __shared__ bhalf_t Bs[4 * 8192];

  // XCD-aware bijective swizzle: 384 blocks, 8 XCDs, 48 contiguous wg/XCD.
  const int bid = blockIdx.x;
  const int wg = (bid & 7) * 48 + (bid >> 3);
  const int seg = wg >> 7;
  const int idx = wg & 127;
  const int bm = idx >> 2, bn = idx & 3;   // bn fast: W-slab L2-resident/XCD

  const bhalf_t *A, *Bw; const float* bias; bhalf_t* out; float scale; int mode;
  if (seg == 0)      { A = Qb; Bw = Wqb; bias = bq; out = qo;  scale = 0.18033688f; mode = 0; }
  else if (seg == 1) { A = Kb; Bw = Wkb; bias = bk; out = ko;  scale = 1.0f;        mode = 0; }
  else               { A = Vb; Bw = Wvb; bias = bv; out = vto; scale = 1.0f;        mode = 1; }

  const int tid = threadIdx.x, lane = tid & 63, w = tid >> 6;   // 8 waves
  const int wm = w >> 2, wn = w & 3;
  const int quad = lane >> 4, tn = lane & 15;

  // staging geometry (verified r1): wave w writes 1KB chunks {w, w+8}/tile;
  // swizzled source chunk c = (lane&7)^(lane>>3); G-row = rA + 128*(c>>2).
  const int c    = (lane & 7) ^ ((lane >> 3) & 7);
  const int rA   = w * 8 + (lane >> 3);
  const int grow = rA + 128 * (c >> 2);
  const int kcol = (c & 3) * 8;
  const bhalf_t* Asrc0 = A  + (size_t)(bm * 256 + grow) * 1024 + kcol;
  const bhalf_t* Asrc1 = Asrc0 + (size_t)64 * 1024;
  const bhalf_t* Bsrc0 = Bw + (size_t)(bn * 256 + grow) * 1024 + kcol;
  const bhalf_t* Bsrc1 = Bsrc0 + (size_t)64 * 1024;

  // read geometry (verified r1): XOR (row&7)=(tn&7) on the 16B chunk slot.
  const int aswz = (((wm << 2) | quad) ^ (tn & 7)) * 8;
  const int bswz = ((((wn >> 1) << 2) | quad) ^ (tn & 7)) * 8;
  const int arow = tn * 64;
  const int brow = (((wn & 1) << 6) + tn) * 64;

  f32x4 acc[8][4];
#pragma unroll
  for (int i = 0; i < 8; ++i)
#pragma unroll
    for (int j = 0; j < 4; ++j)
      acc[i][j] = (f32x4){0.f, 0.f, 0.f, 0.f};

  bf16x8 afA[4], afB[4], bg0[4], bg1[4];

  // prologue: stage tiles 0,1,2 in tile order (A,A,B,B = 4 loads/tile/wave)
#pragma unroll
  for (int t = 0; t < 3; ++t) {
    bhalf_t* And = As + t * 8192;
    bhalf_t* Bnd = Bs + t * 8192;
    GLD16(Asrc0 + t * 32, And + w * 512);
    GLD16(Asrc1 + t * 32, And + (w + 8) * 512);
    GLD16(Bsrc0 + t * 32, Bnd + w * 512);
    GLD16(Bsrc1 + t * 32, Bnd + (w + 8) * 512);
  }
  VMW(4); SB0();   // tiles 0,1 landed; tile 2 (4 loads) in flight
  BARX();
  // prime tile-0 phase-1 fragments
#pragma unroll
  for (int i = 0; i < 4; ++i)
    afA[i] = *(const bf16x8*)(As + arow + i * 1024 + aswz);
#pragma unroll
  for (int j = 0; j < 4; ++j)
    bg0[j] = *(const bf16x8*)(Bs + brow + j * 1024 + bswz);

  // main loop: tiles 0..27 in pairs (even uses bg0, odd bg1)
#pragma unroll 1
  for (int t = 0; t < 28; t += 2) {
    PH1(t, bg0, true);
    PH2(t, bg0, bg1, true, true, VMW(4), true);
    PH1(t + 1, bg1, true);
    PH2(t + 1, bg1, bg0, true, true, VMW(4), true);
  }
  // tail tiles 28..31 (drain: stop issuing, then relax gates)
  PH1(28, bg0, true);
  PH2(28, bg0, bg1, true, true, VMW(4), true);    // tile 30 landed
  PH1(29, bg1, false);
  PH2(29, bg1, bg0, false, true, VMW(0), true);   // tile 31 landed
  PH1(30, bg0, false);
  PH2(30, bg0, bg1, false, true, (void)0, true);
  PH1(31, bg1, false);
  PH2(31, bg1, bg0, false, false, (void)0, false);

  // epilogue: bias + scale, mode-dependent scatter (verified r0/r1)
#pragma unroll
  for (int i = 0; i < 8; ++i)
#pragma unroll
    for (int j = 0; j < 4; ++j) {
      const int n = bn * 256 + wn * 64 + j * 16 + tn;
      const float bsv = bias[n];
      const int h = n >> 6, dk = n & 63;
#pragma unroll
      for (int r = 0; r < 4; ++r) {
        const int m = bm * 256 + wm * 128 + i * 16 + quad * 4 + r;
        const int b = m >> 11, s = m & 2047;
        const float v = (acc[i][j][r] + bsv) * scale;
        size_t addr;
        if (mode == 0) addr = (((size_t)(b * 16 + h)) * 2048 + s) * 64 + dk;
        else {
          const int s2 = (s & ~12) | ((s & 4) << 1) | ((s & 8) >> 1);  // sigma
          addr = (((size_t)(b * 16 + h)) * 64 + dk) * 2048 + s2;
        }
        out[addr] = (bhalf_t)v;
      }
    }
}

// ---------------------------------------------------------------------------
__global__ __launch_bounds__(256) void out_gemm(
    const bhalf_t* __restrict__ A, const bhalf_t* __restrict__ Bw,
    const float* __restrict__ bias, float* __restrict__ Cout)
{
  __shared__ bhalf_t As[4096];
  __shared__ bhalf_t Bs[4096];
  const int bm = blockIdx.x & 63, bn = blockIdx.x >> 6;   // XCD-aware

  f32x4 acc[4][4];
#pragma unroll
  for (int i = 0; i < 4; ++i)
#pragma unroll
    for (int j = 0; j < 4; ++j)
      acc[i][j] = (f32x4){0.f, 0.f, 0.f, 0.f};

  gemm_core_128(A, Bw, bm, bn, As, Bs, acc);

  const int lane = threadIdx.x & 63, wave = threadIdx.x >> 6;
  const int wm = wave >> 1, wn = wave & 1, quad = lane >> 4, tn = lane & 15;
#pragma unroll
  for (int i = 0; i < 4; ++i)
#pragma unroll
    for (int j = 0; j < 4; ++j) {
      const int n = bn * 128 + wn * 64 + j * 16 + tn;
      const float bsv = bias[n];
#pragma unroll
      for (int r = 0; r < 4; ++r) {
        const int m = bm * 128 + wm * 64 + i * 16 + quad * 4 + r;
        Cout[(size_t)m * 1024 + n] = acc[i][j][r] + bsv;
      }
    }
}

// ---------------------------------------------------------------------------
// Flash attention v3.  Block = 4 waves x 64 q rows = 256 q; kv tiles of 64.
// S^T = K @ Q^T (A=K LDS, B=Q regs).  P stays in registers: V^T is stored
// sigma-permuted so the S^T C-layout regs [8kb..8kb+7], exp'd+packed, ARE the
// PV B-fragment for k-block kb.  O^T = Vt @ P accumulates in regs.
// ---------------------------------------------------------------------------
__global__ __launch_bounds__(256, 2) void attn_kernel(
    const bhalf_t* __restrict__ qp, const bhalf_t* __restrict__ kp,
    const bhalf_t* __restrict__ vtp, bhalf_t* __restrict__ outp)
{
  __shared__ bhalf_t Klds[4096];    // [64 kv][64 dk], 16B chunks XOR-swizzled
  __shared__ bhalf_t Vtlds[4096];   // [64 dk][64 kv(sigma)], XOR-swizzled

  const int tid = threadIdx.x, lane = tid & 63, wave = tid >> 6;
  const int q31 = lane & 31, h = lane >> 5;
  const int bh = blockIdx.y, qt = blockIdx.x;

  // Q B-fragments: qf[qset][ks][j] = Q[srow][ks*16 + h*8 + j]
  const bhalf_t* qbase = qp + (((size_t)bh * 2048) + qt * 256 + wave * 64 + q31) * 64;
  bf16x8 qf[2][4];
#pragma unroll
  for (int qs = 0; qs < 2; ++qs)
#pragma unroll
    for (int ks = 0; ks < 4; ++ks)
      qf[qs][ks] = *(const bf16x8*)(qbase + qs * 32 * 64 + ks * 16 + h * 8);

  f32x16 Ot[2][2];
#pragma unroll
  for (int qs = 0; qs < 2; ++qs)
#pragma unroll
    for (int dd = 0; dd < 2; ++dd)
#pragma unroll
      for (int i = 0; i < 16; ++i) Ot[qs][dd][i] = 0.f;
  float Lp[2] = {0.f, 0.f};

  const bhalf_t* kbase  = kp  + (size_t)bh * 2048 * 64;
  const bhalf_t* vtbase = vtp + (size_t)bh * 64 * 2048;

  const int rloc = lane >> 3;                 // staging row within 8-row chunk
  const int cg8  = ((lane & 7) ^ rloc) * 8;   // swizzled source chunk (elems)
  const int q7 = q31 & 7;

  for (int kv0 = 0; kv0 < 2048; kv0 += 64) {
    // stage K [64][64] and Vt [64][64]: 16 x 1KB GLD16 per block
#pragma unroll
    for (int i = 0; i < 2; ++i) {
      const int r0 = (wave * 2 + i) * 8;
      GLD16(kbase + (size_t)(kv0 + r0 + rloc) * 64 + cg8, Klds + r0 * 64);
      GLD16(vtbase + (size_t)(r0 + rloc) * 2048 + kv0 + cg8, Vtlds + r0 * 64);
    }
    __syncthreads();

    // S^T + exp2 + pack into PV B-fragments (register-only)
    bf16x8 pb[2][4];
#pragma unroll
    for (int mb = 0; mb < 2; ++mb) {
      bf16x8 ka[4];
#pragma unroll
      for (int ks = 0; ks < 4; ++ks)
        ka[ks] = *(const bf16x8*)(Klds + (mb * 32 + q31) * 64 + ((2 * ks + h) ^ q7) * 8);
#pragma unroll
      for (int qs = 0; qs < 2; ++qs) {
        f32x16 S;
#pragma unroll
        for (int i = 0; i < 16; ++i) S[i] = 0.f;
#pragma unroll
        for (int ks = 0; ks < 4; ++ks)
          S = __builtin_amdgcn_mfma_f32_32x32x16_bf16(ka[ks], qf[qs][ks], S, 0, 0, 0);
        float ls = 0.f;
#pragma unroll
        for (int half = 0; half < 2; ++half) {
          bf16x8 pk;
#pragma unroll
          for (int j = 0; j < 8; ++j) {
            const float e = __builtin_amdgcn_exp2f(S[half * 8 + j]);
            ls += e;
            pk[j] = (bhalf_t)e;
          }
          pb[qs][mb * 2 + half] = pk;
        }
        Lp[qs] += ls;
      }
    }

    // O^T += Vt @ P   (A-frag k-order matches sigma-permuted storage)
#pragma unroll
    for (int dd = 0; dd < 2; ++dd)
#pragma unroll
      for (int kb = 0; kb < 4; ++kb) {
        const bf16x8 va = *(const bf16x8*)(Vtlds + (dd * 32 + q31) * 64 + ((2 * kb + h) ^ q7) * 8);
#pragma unroll
        for (int qs = 0; qs < 2; ++qs)
          Ot[qs][dd] = __builtin_amdgcn_mfma_f32_32x32x16_bf16(va, pb[qs][kb], Ot[qs][dd], 0, 0, 0);
      }
    __syncthreads();
  }

  // normalize (per-lane q) and store packed bf16x4
  const int b = bh >> 4, hh = bh & 15;
#pragma unroll
  for (int qs = 0; qs < 2; ++qs) {
    const float Lt = Lp[qs] + __shfl_xor(Lp[qs], 32, 64);
    const float linv = 1.0f / Lt;
    const int s = qt * 256 + wave * 64 + qs * 32 + q31;
    bhalf_t* ob = outp + ((size_t)(b * 2048 + s)) * 1024 + hh * 64;
#pragma unroll
    for (int dd = 0; dd < 2; ++dd)
#pragma unroll
      for (int g = 0; g < 4; ++g) {
        bf16x4 o;
        o.x = (bhalf_t)(Ot[qs][dd][4 * g + 0] * linv);
        o.y = (bhalf_t)(Ot[qs][dd][4 * g + 1] * linv);
        o.z = (bhalf_t)(Ot[qs][dd][4 * g + 2] * linv);
        o.w = (bhalf_t)(Ot[qs][dd][4 * g + 3] * linv);
        *(bf16x4*)(ob + dd * 32 + g * 8 + h * 4) = o;
      }
  }
}

// ---------------------------------------------------------------------------
extern "C" void kernel_launch(void* const* d_in, const int* in_sizes, int n_in,
                              void* d_out, int out_size, void* d_ws, size_t ws_size,
                              hipStream_t stream)
{
  const float* Q  = (const float*)d_in[0];
  const float* K  = (const float*)d_in[1];
  const float* V  = (const float*)d_in[2];
  const float* Wq = (const float*)d_in[3];
  const float* bq = (const float*)d_in[4];
  const float* Wk = (const float*)d_in[5];
  const float* bk = (const float*)d_in[6];
  const float* Wv = (const float*)d_in[7];
  const float* bv = (const float*)d_in[8];
  const float* Wo = (const float*)d_in[9];
  const float* bo = (const float*)d_in[10];

  char* ws = (char*)d_ws;
  const size_t SZ = 8192ull * 1024 * 2;   // 16 MB  [8192,1024] bf16
  const size_t WZ = 1024ull * 1024 * 2;   //  2 MB  [1024,1024] bf16
  bhalf_t* Qb   = (bhalf_t*)(ws);
  bhalf_t* Kb   = (bhalf_t*)(ws + SZ);
  bhalf_t* Vb   = (bhalf_t*)(ws + 2 * SZ);
  bhalf_t* Wqb  = (bhalf_t*)(ws + 3 * SZ);
  bhalf_t* Wkb  = (bhalf_t*)(ws + 3 * SZ + WZ);
  bhalf_t* Wvb  = (bhalf_t*)(ws + 3 * SZ + 2 * WZ);
  bhalf_t* Wob  = (bhalf_t*)(ws + 3 * SZ + 3 * WZ);
  bhalf_t* q_p  = (bhalf_t*)(ws + 3 * SZ + 4 * WZ);
  bhalf_t* k_p  = (bhalf_t*)(ws + 4 * SZ + 4 * WZ);
  bhalf_t* vt_p = (bhalf_t*)(ws + 5 * SZ + 4 * WZ);
  bhalf_t* attn_o = Qb;   // alias: Qb is dead after proj_gemm

  cvt_all<<<28672, 256, 0, stream>>>(Q, K, V, Wq, Wk, Wv, Wo,
                                     Qb, Kb, Vb, Wqb, Wkb, Wvb, Wob);
  proj_gemm<<<384, 512, 0, stream>>>(Qb, Kb, Vb, Wqb, Wkb, Wvb,
                                     bq, bk, bv, q_p, k_p, vt_p);
  attn_kernel<<<dim3(8, 64), 256, 0, stream>>>(q_p, k_p, vt_p, attn_o);
  out_gemm<<<512, 256, 0, stream>>>(attn_o, Wob, bo, (float*)d_out);
}

// Round 3
// 356.203 us; speedup vs baseline: 1.0542x; 1.0542x over previous
//
#include <hip/hip_runtime.h>

// B=4, S=2048, D=1024, H=16, Dk=64.  M = B*S = 8192.
// cvt_w(fp32->bf16, weights only) -> proj GEMMs (m97 128^2 core, A read
// directly as fp32 + in-reg cvt + swizzled ds_write; B via GLD16 with
// pre-swizzled source; q/k [bh][s][dk], v^T sigma-permuted [bh][dk][s],
// q pre-scaled 0.125*log2e) -> flash attn v3 (S^T 32x32x16, P-in-regs via
// sigma trick, 64 q/wave) -> out GEMM (swizzled 128^2 core).
//
// LDS layout (both A and B tiles, 8 KB each): rows r and r+64 paired into
// 128B lines: row' = r&63, 8 slots of 16B, slot = (4*(r>>6) + kchunk) ^ (r&7).
// ds_read_b128 fragment reads then spread over all 8 slots (2 lanes/slot =
// 2-way = free; r1/r2 measured 0 conflicts with this bijection).  GLD16
// keeps a LINEAR LDS dest (HW requirement); the permutation is baked into
// the per-lane GLOBAL source address.  Reg-staged A writes b128 linearly.

typedef __bf16 bhalf_t;
typedef __attribute__((ext_vector_type(8)))  __bf16 bf16x8;
typedef __attribute__((ext_vector_type(4)))  __bf16 bf16x4;
typedef __attribute__((ext_vector_type(4)))  float  f32x4;
typedef __attribute__((ext_vector_type(16))) float  f32x16;

typedef __attribute__((address_space(1))) void gvoid_t;
typedef __attribute__((address_space(3))) void lvoid_t;
#define GLD16(g, l) __builtin_amdgcn_global_load_lds((const gvoid_t*)(g), (lvoid_t*)(l), 16, 0, 0)

// ---------------------------------------------------------------------------
// Weights-only fp32 -> bf16 (4 x [1024x1024]); Q/K/V convert inside proj.
// ---------------------------------------------------------------------------
__global__ __launch_bounds__(256) void cvt_w(
    const float* __restrict__ Wq, const float* __restrict__ Wk,
    const float* __restrict__ Wv, const float* __restrict__ Wo,
    bhalf_t* __restrict__ Wqb, bhalf_t* __restrict__ Wkb,
    bhalf_t* __restrict__ Wvb, bhalf_t* __restrict__ Wob)
{
  size_t t = (size_t)blockIdx.x * 256 + threadIdx.x;   // float4 index
  int w = (int)(t >> 18); t &= 262143;
  const float* src = (w == 0) ? Wq  : (w == 1) ? Wk  : (w == 2) ? Wv  : Wo;
  bhalf_t*     dst = (w == 0) ? Wqb : (w == 1) ? Wkb : (w == 2) ? Wvb : Wob;
  float4 f = ((const float4*)src)[t];
  bf16x4 o;
  o.x = (bhalf_t)f.x; o.y = (bhalf_t)f.y; o.z = (bhalf_t)f.z; o.w = (bhalf_t)f.w;
  ((bf16x4*)dst)[t] = o;
}

// ---------------------------------------------------------------------------
// Swizzled m97 core (bf16 A and B via GLD16): C[128x128] of A[M,1024] @ B^T.
// Used by out_gemm.
// ---------------------------------------------------------------------------
__device__ __forceinline__ void gemm_core_128_swz(
    const bhalf_t* __restrict__ A, const bhalf_t* __restrict__ B,
    int bm, int bn, bhalf_t* As, bhalf_t* Bs, f32x4 acc[4][4])
{
  const int tid = threadIdx.x, lane = tid & 63, wave = tid >> 6;
  const int wm = wave >> 1, wn = wave & 1;
  const int quad = lane >> 4, tn = lane & 15;

  // staging: chunk c (= wave, wave+4) covers row-pairs r' = c*8 + (lane>>3);
  // linear LDS dest slot (lane&7) must hold u = (lane&7)^(lane>>3):
  //   source row = r' + 64*(u>>2), k-chunk = u&3.
  const int u    = (lane & 7) ^ (lane >> 3);
  const int roff = (lane >> 3) + 64 * (u >> 2);
  const int gk   = (u & 3) * 8;

  const bhalf_t* Ag0 = A + (size_t)(bm * 128 + wave * 8 + roff) * 1024 + gk;
  const bhalf_t* Ag1 = A + (size_t)(bm * 128 + (wave + 4) * 8 + roff) * 1024 + gk;
  const bhalf_t* Bg0 = B + (size_t)(bn * 128 + wave * 8 + roff) * 1024 + gk;
  const bhalf_t* Bg1 = B + (size_t)(bn * 128 + (wave + 4) * 8 + roff) * 1024 + gk;
  bhalf_t* Ad0 = As + wave * 512;  bhalf_t* Ad1 = As + (wave + 4) * 512;
  bhalf_t* Bd0 = Bs + wave * 512;  bhalf_t* Bd1 = Bs + (wave + 4) * 512;

  // fragment reads: row r = half*64 + i*16 + tn -> row' = i*16+tn,
  // slot = (4*half + quad) ^ (tn&7).
  const int aswz = ((wm * 4 + quad) ^ (tn & 7)) * 8;
  const int bswz = ((wn * 4 + quad) ^ (tn & 7)) * 8;

  for (int k0 = 0; k0 < 1024; k0 += 32) {
    GLD16(Ag0 + k0, Ad0);
    GLD16(Ag1 + k0, Ad1);
    GLD16(Bg0 + k0, Bd0);
    GLD16(Bg1 + k0, Bd1);
    __syncthreads();
    bf16x8 af[4], bfr[4];
#pragma unroll
    for (int i = 0; i < 4; ++i)
      af[i] = *(const bf16x8*)(As + (i * 16 + tn) * 64 + aswz);
#pragma unroll
    for (int j = 0; j < 4; ++j)
      bfr[j] = *(const bf16x8*)(Bs + (j * 16 + tn) * 64 + bswz);
#pragma unroll
    for (int i = 0; i < 4; ++i)
#pragma unroll
      for (int j = 0; j < 4; ++j)
        acc[i][j] = __builtin_amdgcn_mfma_f32_16x16x32_bf16(af[i], bfr[j], acc[i][j], 0, 0, 0);
    __syncthreads();
  }
}

// ---------------------------------------------------------------------------
// Fused q/k/v projection.  A = fp32 Q/K/V read directly (no cvt pass):
// reg-staged (global fp32 -> cvt -> ds_write_b128, swizzle on the LDS
// address mapping via pre-swizzled source rows).  B = bf16 weights via
// GLD16 with pre-swizzled source.  q scaled by 0.125*log2e; v stored
// transposed [bh][dk][s] with s sigma-permuted (swap bits 2<->3).
// Block mapping: bm = idx&63 (fast) so XCD = bm%8 -> per-XCD A-slab reuse.
// ---------------------------------------------------------------------------
__global__ __launch_bounds__(256) void proj_gemm(
    const float* __restrict__ Qf, const float* __restrict__ Kf, const float* __restrict__ Vf,
    const bhalf_t* __restrict__ Wqb, const bhalf_t* __restrict__ Wkb, const bhalf_t* __restrict__ Wvb,
    const float* __restrict__ bq, const float* __restrict__ bk, const float* __restrict__ bv,
    bhalf_t* __restrict__ qo, bhalf_t* __restrict__ ko, bhalf_t* __restrict__ vto)
{
  __shared__ bhalf_t As[4096];
  __shared__ bhalf_t Bs[4096];
  const int seg = blockIdx.x >> 9;
  const int idx = blockIdx.x & 511;
  const int bm = idx & 63, bn = idx >> 6;    // XCD-aware: bm fast-varying

  const float *A; const bhalf_t *Bw; const float* bias; bhalf_t* out; float scale; int mode;
  if (seg == 0)      { A = Qf; Bw = Wqb; bias = bq; out = qo;  scale = 0.18033688f; mode = 0; }
  else if (seg == 1) { A = Kf; Bw = Wkb; bias = bk; out = ko;  scale = 1.0f;        mode = 0; }
  else               { A = Vf; Bw = Wvb; bias = bv; out = vto; scale = 1.0f;        mode = 1; }

  const int tid = threadIdx.x, lane = tid & 63, wave = tid >> 6;
  const int wm = wave >> 1, wn = wave & 1;
  const int quad = lane >> 4, tn = lane & 15;

  const int u    = (lane & 7) ^ (lane >> 3);
  const int roff = (lane >> 3) + 64 * (u >> 2);
  const int gk   = (u & 3) * 8;

  // A source (fp32), chunks wave and wave+4; dest linear b128 per lane.
  const float* Af0 = A + (size_t)(bm * 128 + wave * 8 + roff) * 1024 + gk;
  const float* Af1 = A + (size_t)(bm * 128 + (wave + 4) * 8 + roff) * 1024 + gk;
  bhalf_t* Ad0 = As + wave * 512 + lane * 8;
  bhalf_t* Ad1 = As + (wave + 4) * 512 + lane * 8;
  // B source (bf16) via GLD16, pre-swizzled source rows.
  const bhalf_t* Bg0 = Bw + (size_t)(bn * 128 + wave * 8 + roff) * 1024 + gk;
  const bhalf_t* Bg1 = Bw + (size_t)(bn * 128 + (wave + 4) * 8 + roff) * 1024 + gk;
  bhalf_t* Bd0 = Bs + wave * 512;
  bhalf_t* Bd1 = Bs + (wave + 4) * 512;

  const int aswz = ((wm * 4 + quad) ^ (tn & 7)) * 8;
  const int bswz = ((wn * 4 + quad) ^ (tn & 7)) * 8;

  f32x4 acc[4][4];
#pragma unroll
  for (int i = 0; i < 4; ++i)
#pragma unroll
    for (int j = 0; j < 4; ++j)
      acc[i][j] = (f32x4){0.f, 0.f, 0.f, 0.f};

  for (int k0 = 0; k0 < 1024; k0 += 32) {
    GLD16(Bg0 + k0, Bd0);
    GLD16(Bg1 + k0, Bd1);
    float4 a00 = *(const float4*)(Af0 + k0);
    float4 a01 = *(const float4*)(Af0 + k0 + 4);
    float4 a10 = *(const float4*)(Af1 + k0);
    float4 a11 = *(const float4*)(Af1 + k0 + 4);
    bf16x8 v0, v1;
    v0[0] = (bhalf_t)a00.x; v0[1] = (bhalf_t)a00.y;
    v0[2] = (bhalf_t)a00.z; v0[3] = (bhalf_t)a00.w;
    v0[4] = (bhalf_t)a01.x; v0[5] = (bhalf_t)a01.y;
    v0[6] = (bhalf_t)a01.z; v0[7] = (bhalf_t)a01.w;
    v1[0] = (bhalf_t)a10.x; v1[1] = (bhalf_t)a10.y;
    v1[2] = (bhalf_t)a10.z; v1[3] = (bhalf_t)a10.w;
    v1[4] = (bhalf_t)a11.x; v1[5] = (bhalf_t)a11.y;
    v1[6] = (bhalf_t)a11.z; v1[7] = (bhalf_t)a11.w;
    *(bf16x8*)Ad0 = v0;
    *(bf16x8*)Ad1 = v1;
    __syncthreads();
    bf16x8 af[4], bfr[4];
#pragma unroll
    for (int i = 0; i < 4; ++i)
      af[i] = *(const bf16x8*)(As + (i * 16 + tn) * 64 + aswz);
#pragma unroll
    for (int j = 0; j < 4; ++j)
      bfr[j] = *(const bf16x8*)(Bs + (j * 16 + tn) * 64 + bswz);
#pragma unroll
    for (int i = 0; i < 4; ++i)
#pragma unroll
      for (int j = 0; j < 4; ++j)
        acc[i][j] = __builtin_amdgcn_mfma_f32_16x16x32_bf16(af[i], bfr[j], acc[i][j], 0, 0, 0);
    __syncthreads();
  }

  // epilogue: bias + scale, mode-dependent scatter (verified r0)
#pragma unroll
  for (int i = 0; i < 4; ++i)
#pragma unroll
    for (int j = 0; j < 4; ++j) {
      const int n = bn * 128 + wn * 64 + j * 16 + tn;
      const float bsv = bias[n];
      const int h = n >> 6, dk = n & 63;
#pragma unroll
      for (int r = 0; r < 4; ++r) {
        const int m = bm * 128 + wm * 64 + i * 16 + quad * 4 + r;
        const int b = m >> 11, s = m & 2047;
        const float v = (acc[i][j][r] + bsv) * scale;
        size_t addr;
        if (mode == 0) addr = (((size_t)(b * 16 + h)) * 2048 + s) * 64 + dk;
        else {
          const int s2 = (s & ~12) | ((s & 4) << 1) | ((s & 8) >> 1);  // sigma
          addr = (((size_t)(b * 16 + h)) * 64 + dk) * 2048 + s2;
        }
        out[addr] = (bhalf_t)v;
      }
    }
}

// ---------------------------------------------------------------------------
__global__ __launch_bounds__(256) void out_gemm(
    const bhalf_t* __restrict__ A, const bhalf_t* __restrict__ Bw,
    const float* __restrict__ bias, float* __restrict__ Cout)
{
  __shared__ bhalf_t As[4096];
  __shared__ bhalf_t Bs[4096];
  const int bm = blockIdx.x & 63, bn = blockIdx.x >> 6;   // XCD-aware

  f32x4 acc[4][4];
#pragma unroll
  for (int i = 0; i < 4; ++i)
#pragma unroll
    for (int j = 0; j < 4; ++j)
      acc[i][j] = (f32x4){0.f, 0.f, 0.f, 0.f};

  gemm_core_128_swz(A, Bw, bm, bn, As, Bs, acc);

  const int lane = threadIdx.x & 63, wave = threadIdx.x >> 6;
  const int wm = wave >> 1, wn = wave & 1, quad = lane >> 4, tn = lane & 15;
#pragma unroll
  for (int i = 0; i < 4; ++i)
#pragma unroll
    for (int j = 0; j < 4; ++j) {
      const int n = bn * 128 + wn * 64 + j * 16 + tn;
      const float bsv = bias[n];
#pragma unroll
      for (int r = 0; r < 4; ++r) {
        const int m = bm * 128 + wm * 64 + i * 16 + quad * 4 + r;
        Cout[(size_t)m * 1024 + n] = acc[i][j][r] + bsv;
      }
    }
}

// ---------------------------------------------------------------------------
// Flash attention v3 (unchanged, verified).  Block = 4 waves x 64 q rows;
// kv tiles of 64.  S^T = K @ Q^T; P in regs via sigma trick; O^T = Vt @ P.
// ---------------------------------------------------------------------------
__global__ __launch_bounds__(256, 2) void attn_kernel(
    const bhalf_t* __restrict__ qp, const bhalf_t* __restrict__ kp,
    const bhalf_t* __restrict__ vtp, bhalf_t* __restrict__ outp)
{
  __shared__ bhalf_t Klds[4096];    // [64 kv][64 dk], 16B chunks XOR-swizzled
  __shared__ bhalf_t Vtlds[4096];   // [64 dk][64 kv(sigma)], XOR-swizzled

  const int tid = threadIdx.x, lane = tid & 63, wave = tid >> 6;
  const int q31 = lane & 31, h = lane >> 5;
  const int bh = blockIdx.y, qt = blockIdx.x;

  const bhalf_t* qbase = qp + (((size_t)bh * 2048) + qt * 256 + wave * 64 + q31) * 64;
  bf16x8 qf[2][4];
#pragma unroll
  for (int qs = 0; qs < 2; ++qs)
#pragma unroll
    for (int ks = 0; ks < 4; ++ks)
      qf[qs][ks] = *(const bf16x8*)(qbase + qs * 32 * 64 + ks * 16 + h * 8);

  f32x16 Ot[2][2];
#pragma unroll
  for (int qs = 0; qs < 2; ++qs)
#pragma unroll
    for (int dd = 0; dd < 2; ++dd)
#pragma unroll
      for (int i = 0; i < 16; ++i) Ot[qs][dd][i] = 0.f;
  float Lp[2] = {0.f, 0.f};

  const bhalf_t* kbase  = kp  + (size_t)bh * 2048 * 64;
  const bhalf_t* vtbase = vtp + (size_t)bh * 64 * 2048;

  const int rloc = lane >> 3;                 // staging row within 8-row chunk
  const int cg8  = ((lane & 7) ^ rloc) * 8;   // swizzled source chunk (elems)
  const int q7 = q31 & 7;

  for (int kv0 = 0; kv0 < 2048; kv0 += 64) {
#pragma unroll
    for (int i = 0; i < 2; ++i) {
      const int r0 = (wave * 2 + i) * 8;
      GLD16(kbase + (size_t)(kv0 + r0 + rloc) * 64 + cg8, Klds + r0 * 64);
      GLD16(vtbase + (size_t)(r0 + rloc) * 2048 + kv0 + cg8, Vtlds + r0 * 64);
    }
    __syncthreads();

    bf16x8 pb[2][4];
#pragma unroll
    for (int mb = 0; mb < 2; ++mb) {
      bf16x8 ka[4];
#pragma unroll
      for (int ks = 0; ks < 4; ++ks)
        ka[ks] = *(const bf16x8*)(Klds + (mb * 32 + q31) * 64 + ((2 * ks + h) ^ q7) * 8);
#pragma unroll
      for (int qs = 0; qs < 2; ++qs) {
        f32x16 S;
#pragma unroll
        for (int i = 0; i < 16; ++i) S[i] = 0.f;
#pragma unroll
        for (int ks = 0; ks < 4; ++ks)
          S = __builtin_amdgcn_mfma_f32_32x32x16_bf16(ka[ks], qf[qs][ks], S, 0, 0, 0);
        float ls = 0.f;
#pragma unroll
        for (int half = 0; half < 2; ++half) {
          bf16x8 pk;
#pragma unroll
          for (int j = 0; j < 8; ++j) {
            const float e = __builtin_amdgcn_exp2f(S[half * 8 + j]);
            ls += e;
            pk[j] = (bhalf_t)e;
          }
          pb[qs][mb * 2 + half] = pk;
        }
        Lp[qs] += ls;
      }
    }

#pragma unroll
    for (int dd = 0; dd < 2; ++dd)
#pragma unroll
      for (int kb = 0; kb < 4; ++kb) {
        const bf16x8 va = *(const bf16x8*)(Vtlds + (dd * 32 + q31) * 64 + ((2 * kb + h) ^ q7) * 8);
#pragma unroll
        for (int qs = 0; qs < 2; ++qs)
          Ot[qs][dd] = __builtin_amdgcn_mfma_f32_32x32x16_bf16(va, pb[qs][kb], Ot[qs][dd], 0, 0, 0);
      }
    __syncthreads();
  }

  const int b = bh >> 4, hh = bh & 15;
#pragma unroll
  for (int qs = 0; qs < 2; ++qs) {
    const float Lt = Lp[qs] + __shfl_xor(Lp[qs], 32, 64);
    const float linv = 1.0f / Lt;
    const int s = qt * 256 + wave * 64 + qs * 32 + q31;
    bhalf_t* ob = outp + ((size_t)(b * 2048 + s)) * 1024 + hh * 64;
#pragma unroll
    for (int dd = 0; dd < 2; ++dd)
#pragma unroll
      for (int g = 0; g < 4; ++g) {
        bf16x4 o;
        o.x = (bhalf_t)(Ot[qs][dd][4 * g + 0] * linv);
        o.y = (bhalf_t)(Ot[qs][dd][4 * g + 1] * linv);
        o.z = (bhalf_t)(Ot[qs][dd][4 * g + 2] * linv);
        o.w = (bhalf_t)(Ot[qs][dd][4 * g + 3] * linv);
        *(bf16x4*)(ob + dd * 32 + g * 8 + h * 4) = o;
      }
  }
}

// ---------------------------------------------------------------------------
extern "C" void kernel_launch(void* const* d_in, const int* in_sizes, int n_in,
                              void* d_out, int out_size, void* d_ws, size_t ws_size,
                              hipStream_t stream)
{
  const float* Q  = (const float*)d_in[0];
  const float* K  = (const float*)d_in[1];
  const float* V  = (const float*)d_in[2];
  const float* Wq = (const float*)d_in[3];
  const float* bq = (const float*)d_in[4];
  const float* Wk = (const float*)d_in[5];
  const float* bk = (const float*)d_in[6];
  const float* Wv = (const float*)d_in[7];
  const float* bv = (const float*)d_in[8];
  const float* Wo = (const float*)d_in[9];
  const float* bo = (const float*)d_in[10];

  char* ws = (char*)d_ws;
  const size_t SZ = 8192ull * 1024 * 2;   // 16 MB  [8192,1024] bf16
  const size_t WZ = 1024ull * 1024 * 2;   //  2 MB  [1024,1024] bf16
  bhalf_t* Wqb  = (bhalf_t*)(ws);
  bhalf_t* Wkb  = (bhalf_t*)(ws + WZ);
  bhalf_t* Wvb  = (bhalf_t*)(ws + 2 * WZ);
  bhalf_t* Wob  = (bhalf_t*)(ws + 3 * WZ);
  bhalf_t* q_p  = (bhalf_t*)(ws + 4 * WZ);
  bhalf_t* k_p  = (bhalf_t*)(ws + 4 * WZ + SZ);
  bhalf_t* vt_p = (bhalf_t*)(ws + 4 * WZ + 2 * SZ);
  bhalf_t* attn_o = (bhalf_t*)(ws + 4 * WZ + 3 * SZ);

  cvt_w<<<4096, 256, 0, stream>>>(Wq, Wk, Wv, Wo, Wqb, Wkb, Wvb, Wob);
  proj_gemm<<<1536, 256, 0, stream>>>(Q, K, V, Wqb, Wkb, Wvb,
                                      bq, bk, bv, q_p, k_p, vt_p);
  attn_kernel<<<dim3(8, 64), 256, 0, stream>>>(q_p, k_p, vt_p, attn_o);
  out_gemm<<<512, 256, 0, stream>>>(attn_o, Wob, bo, (float*)d_out);
}

// Round 4
// 334.786 us; speedup vs baseline: 1.1216x; 1.0640x over previous
//
#include <hip/hip_runtime.h>

// B=4, S=2048, D=1024, H=16, Dk=64.  M = B*S = 8192.
// cvt(fp32->bf16) -> proj GEMMs (q/k [bh][s][dk], v^T sigma-permuted
// [bh][dk][s], q pre-scaled 0.125*log2e) -> flash attn v3 (S^T 32x32x16,
// P-in-regs via sigma trick, 64 q/wave) -> out GEMM.  Workspace: 104 MB.
//
// This is the r0 structure with ONE change: the 128^2 GEMM core uses the
// r3-verified swizzled LDS layout (rows r and r+64 paired into 128B lines;
// 16B slot = (4*(r>>6)+kchunk) ^ (r&7); GLD16 keeps a LINEAR LDS dest with
// the permutation baked into the per-lane GLOBAL source address; ds_read
// applies the same XOR).  r0's [row][32] layout was an 8-way read conflict
// (6.3M SQ_LDS_BANK_CONFLICT); this layout measured 0 in r3.

typedef __bf16 bhalf_t;
typedef __attribute__((ext_vector_type(8)))  __bf16 bf16x8;
typedef __attribute__((ext_vector_type(4)))  __bf16 bf16x4;
typedef __attribute__((ext_vector_type(4)))  float  f32x4;
typedef __attribute__((ext_vector_type(16))) float  f32x16;

typedef __attribute__((address_space(1))) void gvoid_t;
typedef __attribute__((address_space(3))) void lvoid_t;
#define GLD16(g, l) __builtin_amdgcn_global_load_lds((const gvoid_t*)(g), (lvoid_t*)(l), 16, 0, 0)

// ---------------------------------------------------------------------------
__global__ __launch_bounds__(256) void cvt_all(
    const float* __restrict__ Q, const float* __restrict__ Kin, const float* __restrict__ V,
    const float* __restrict__ Wq, const float* __restrict__ Wk, const float* __restrict__ Wv,
    const float* __restrict__ Wo,
    bhalf_t* __restrict__ Qb, bhalf_t* __restrict__ Kb, bhalf_t* __restrict__ Vb,
    bhalf_t* __restrict__ Wqb, bhalf_t* __restrict__ Wkb, bhalf_t* __restrict__ Wvb,
    bhalf_t* __restrict__ Wob)
{
  size_t t = (size_t)blockIdx.x * 256 + threadIdx.x;   // float4 index
  const float* src; bhalf_t* dst;
  if (t < 2097152)      { src = Q;   dst = Qb; }
  else if (t < 4194304) { src = Kin; dst = Kb; t -= 2097152; }
  else if (t < 6291456) { src = V;   dst = Vb; t -= 4194304; }
  else {
    t -= 6291456;
    int w = (int)(t >> 18); t &= 262143;
    src = (w == 0) ? Wq  : (w == 1) ? Wk  : (w == 2) ? Wv  : Wo;
    dst = (w == 0) ? Wqb : (w == 1) ? Wkb : (w == 2) ? Wvb : Wob;
  }
  float4 f = ((const float4*)src)[t];
  bf16x4 o;
  o.x = (bhalf_t)f.x; o.y = (bhalf_t)f.y; o.z = (bhalf_t)f.z; o.w = (bhalf_t)f.w;
  ((bf16x4*)dst)[t] = o;
}

// ---------------------------------------------------------------------------
// Swizzled m97 core (r3-verified): C[128x128] tile of A[M,1024] @ B^T.
// ---------------------------------------------------------------------------
__device__ __forceinline__ void gemm_core_128_swz(
    const bhalf_t* __restrict__ A, const bhalf_t* __restrict__ B,
    int bm, int bn, bhalf_t* As, bhalf_t* Bs, f32x4 acc[4][4])
{
  const int tid = threadIdx.x, lane = tid & 63, wave = tid >> 6;
  const int wm = wave >> 1, wn = wave & 1;
  const int quad = lane >> 4, tn = lane & 15;

  // staging: chunk c (= wave, wave+4) covers row-pairs r' = c*8 + (lane>>3);
  // linear LDS dest slot (lane&7) must hold u = (lane&7)^(lane>>3):
  //   source row = r' + 64*(u>>2), k-chunk = u&3.
  const int u    = (lane & 7) ^ (lane >> 3);
  const int roff = (lane >> 3) + 64 * (u >> 2);
  const int gk   = (u & 3) * 8;

  const bhalf_t* Ag0 = A + (size_t)(bm * 128 + wave * 8 + roff) * 1024 + gk;
  const bhalf_t* Ag1 = A + (size_t)(bm * 128 + (wave + 4) * 8 + roff) * 1024 + gk;
  const bhalf_t* Bg0 = B + (size_t)(bn * 128 + wave * 8 + roff) * 1024 + gk;
  const bhalf_t* Bg1 = B + (size_t)(bn * 128 + (wave + 4) * 8 + roff) * 1024 + gk;
  bhalf_t* Ad0 = As + wave * 512;  bhalf_t* Ad1 = As + (wave + 4) * 512;
  bhalf_t* Bd0 = Bs + wave * 512;  bhalf_t* Bd1 = Bs + (wave + 4) * 512;

  // fragment reads: row r = half*64 + i*16 + tn -> row' = i*16+tn,
  // slot = (4*half + quad) ^ (tn&7).
  const int aswz = ((wm * 4 + quad) ^ (tn & 7)) * 8;
  const int bswz = ((wn * 4 + quad) ^ (tn & 7)) * 8;

  for (int k0 = 0; k0 < 1024; k0 += 32) {
    GLD16(Ag0 + k0, Ad0);
    GLD16(Ag1 + k0, Ad1);
    GLD16(Bg0 + k0, Bd0);
    GLD16(Bg1 + k0, Bd1);
    __syncthreads();
    bf16x8 af[4], bfr[4];
#pragma unroll
    for (int i = 0; i < 4; ++i)
      af[i] = *(const bf16x8*)(As + (i * 16 + tn) * 64 + aswz);
#pragma unroll
    for (int j = 0; j < 4; ++j)
      bfr[j] = *(const bf16x8*)(Bs + (j * 16 + tn) * 64 + bswz);
#pragma unroll
    for (int i = 0; i < 4; ++i)
#pragma unroll
      for (int j = 0; j < 4; ++j)
        acc[i][j] = __builtin_amdgcn_mfma_f32_16x16x32_bf16(af[i], bfr[j], acc[i][j], 0, 0, 0);
    __syncthreads();
  }
}

// ---------------------------------------------------------------------------
// Fused q/k/v projection.  q scaled by 0.125*log2e (attn uses exp2).
// v stored transposed [bh][dk][s] with s sigma-permuted (swap bits 2<->3).
// Block mapping: bm = idx&63 (fast) so XCD = bm%8 -> per-XCD A-slab reuse.
// ---------------------------------------------------------------------------
__global__ __launch_bounds__(256) void proj_gemm(
    const bhalf_t* __restrict__ Qb, const bhalf_t* __restrict__ Kb, const bhalf_t* __restrict__ Vb,
    const bhalf_t* __restrict__ Wqb, const bhalf_t* __restrict__ Wkb, const bhalf_t* __restrict__ Wvb,
    const float* __restrict__ bq, const float* __restrict__ bk, const float* __restrict__ bv,
    bhalf_t* __restrict__ qo, bhalf_t* __restrict__ ko, bhalf_t* __restrict__ vto)
{
  __shared__ bhalf_t As[4096];
  __shared__ bhalf_t Bs[4096];
  const int seg = blockIdx.x >> 9;
  const int idx = blockIdx.x & 511;
  const int bm = idx & 63, bn = idx >> 6;    // XCD-aware: bm fast-varying

  const bhalf_t *A, *Bw; const float* bias; bhalf_t* out; float scale; int mode;
  if (seg == 0)      { A = Qb; Bw = Wqb; bias = bq; out = qo;  scale = 0.18033688f; mode = 0; }
  else if (seg == 1) { A = Kb; Bw = Wkb; bias = bk; out = ko;  scale = 1.0f;        mode = 0; }
  else               { A = Vb; Bw = Wvb; bias = bv; out = vto; scale = 1.0f;        mode = 1; }

  f32x4 acc[4][4];
#pragma unroll
  for (int i = 0; i < 4; ++i)
#pragma unroll
    for (int j = 0; j < 4; ++j)
      acc[i][j] = (f32x4){0.f, 0.f, 0.f, 0.f};

  gemm_core_128_swz(A, Bw, bm, bn, As, Bs, acc);

  const int lane = threadIdx.x & 63, wave = threadIdx.x >> 6;
  const int wm = wave >> 1, wn = wave & 1, quad = lane >> 4, tn = lane & 15;
#pragma unroll
  for (int i = 0; i < 4; ++i)
#pragma unroll
    for (int j = 0; j < 4; ++j) {
      const int n = bn * 128 + wn * 64 + j * 16 + tn;
      const float bsv = bias[n];
      const int h = n >> 6, dk = n & 63;
#pragma unroll
      for (int r = 0; r < 4; ++r) {
        const int m = bm * 128 + wm * 64 + i * 16 + quad * 4 + r;
        const int b = m >> 11, s = m & 2047;
        const float v = (acc[i][j][r] + bsv) * scale;
        size_t addr;
        if (mode == 0) addr = (((size_t)(b * 16 + h)) * 2048 + s) * 64 + dk;
        else {
          const int s2 = (s & ~12) | ((s & 4) << 1) | ((s & 8) >> 1);  // sigma
          addr = (((size_t)(b * 16 + h)) * 64 + dk) * 2048 + s2;
        }
        out[addr] = (bhalf_t)v;
      }
    }
}

// ---------------------------------------------------------------------------
__global__ __launch_bounds__(256) void out_gemm(
    const bhalf_t* __restrict__ A, const bhalf_t* __restrict__ Bw,
    const float* __restrict__ bias, float* __restrict__ Cout)
{
  __shared__ bhalf_t As[4096];
  __shared__ bhalf_t Bs[4096];
  const int bm = blockIdx.x & 63, bn = blockIdx.x >> 6;   // XCD-aware

  f32x4 acc[4][4];
#pragma unroll
  for (int i = 0; i < 4; ++i)
#pragma unroll
    for (int j = 0; j < 4; ++j)
      acc[i][j] = (f32x4){0.f, 0.f, 0.f, 0.f};

  gemm_core_128_swz(A, Bw, bm, bn, As, Bs, acc);

  const int lane = threadIdx.x & 63, wave = threadIdx.x >> 6;
  const int wm = wave >> 1, wn = wave & 1, quad = lane >> 4, tn = lane & 15;
#pragma unroll
  for (int i = 0; i < 4; ++i)
#pragma unroll
    for (int j = 0; j < 4; ++j) {
      const int n = bn * 128 + wn * 64 + j * 16 + tn;
      const float bsv = bias[n];
#pragma unroll
      for (int r = 0; r < 4; ++r) {
        const int m = bm * 128 + wm * 64 + i * 16 + quad * 4 + r;
        Cout[(size_t)m * 1024 + n] = acc[i][j][r] + bsv;
      }
    }
}

// ---------------------------------------------------------------------------
// Flash attention v3 (unchanged, verified).  Block = 4 waves x 64 q rows;
// kv tiles of 64.  S^T = K @ Q^T; P in regs via sigma trick; O^T = Vt @ P.
// ---------------------------------------------------------------------------
__global__ __launch_bounds__(256, 2) void attn_kernel(
    const bhalf_t* __restrict__ qp, const bhalf_t* __restrict__ kp,
    const bhalf_t* __restrict__ vtp, bhalf_t* __restrict__ outp)
{
  __shared__ bhalf_t Klds[4096];    // [64 kv][64 dk], 16B chunks XOR-swizzled
  __shared__ bhalf_t Vtlds[4096];   // [64 dk][64 kv(sigma)], XOR-swizzled

  const int tid = threadIdx.x, lane = tid & 63, wave = tid >> 6;
  const int q31 = lane & 31, h = lane >> 5;
  const int bh = blockIdx.y, qt = blockIdx.x;

  const bhalf_t* qbase = qp + (((size_t)bh * 2048) + qt * 256 + wave * 64 + q31) * 64;
  bf16x8 qf[2][4];
#pragma unroll
  for (int qs = 0; qs < 2; ++qs)
#pragma unroll
    for (int ks = 0; ks < 4; ++ks)
      qf[qs][ks] = *(const bf16x8*)(qbase + qs * 32 * 64 + ks * 16 + h * 8);

  f32x16 Ot[2][2];
#pragma unroll
  for (int qs = 0; qs < 2; ++qs)
#pragma unroll
    for (int dd = 0; dd < 2; ++dd)
#pragma unroll
      for (int i = 0; i < 16; ++i) Ot[qs][dd][i] = 0.f;
  float Lp[2] = {0.f, 0.f};

  const bhalf_t* kbase  = kp  + (size_t)bh * 2048 * 64;
  const bhalf_t* vtbase = vtp + (size_t)bh * 64 * 2048;

  const int rloc = lane >> 3;                 // staging row within 8-row chunk
  const int cg8  = ((lane & 7) ^ rloc) * 8;   // swizzled source chunk (elems)
  const int q7 = q31 & 7;

  for (int kv0 = 0; kv0 < 2048; kv0 += 64) {
#pragma unroll
    for (int i = 0; i < 2; ++i) {
      const int r0 = (wave * 2 + i) * 8;
      GLD16(kbase + (size_t)(kv0 + r0 + rloc) * 64 + cg8, Klds + r0 * 64);
      GLD16(vtbase + (size_t)(r0 + rloc) * 2048 + kv0 + cg8, Vtlds + r0 * 64);
    }
    __syncthreads();

    bf16x8 pb[2][4];
#pragma unroll
    for (int mb = 0; mb < 2; ++mb) {
      bf16x8 ka[4];
#pragma unroll
      for (int ks = 0; ks < 4; ++ks)
        ka[ks] = *(const bf16x8*)(Klds + (mb * 32 + q31) * 64 + ((2 * ks + h) ^ q7) * 8);
#pragma unroll
      for (int qs = 0; qs < 2; ++qs) {
        f32x16 S;
#pragma unroll
        for (int i = 0; i < 16; ++i) S[i] = 0.f;
#pragma unroll
        for (int ks = 0; ks < 4; ++ks)
          S = __builtin_amdgcn_mfma_f32_32x32x16_bf16(ka[ks], qf[qs][ks], S, 0, 0, 0);
        float ls = 0.f;
#pragma unroll
        for (int half = 0; half < 2; ++half) {
          bf16x8 pk;
#pragma unroll
          for (int j = 0; j < 8; ++j) {
            const float e = __builtin_amdgcn_exp2f(S[half * 8 + j]);
            ls += e;
            pk[j] = (bhalf_t)e;
          }
          pb[qs][mb * 2 + half] = pk;
        }
        Lp[qs] += ls;
      }
    }

#pragma unroll
    for (int dd = 0; dd < 2; ++dd)
#pragma unroll
      for (int kb = 0; kb < 4; ++kb) {
        const bf16x8 va = *(const bf16x8*)(Vtlds + (dd * 32 + q31) * 64 + ((2 * kb + h) ^ q7) * 8);
#pragma unroll
        for (int qs = 0; qs < 2; ++qs)
          Ot[qs][dd] = __builtin_amdgcn_mfma_f32_32x32x16_bf16(va, pb[qs][kb], Ot[qs][dd], 0, 0, 0);
      }
    __syncthreads();
  }

  const int b = bh >> 4, hh = bh & 15;
#pragma unroll
  for (int qs = 0; qs < 2; ++qs) {
    const float Lt = Lp[qs] + __shfl_xor(Lp[qs], 32, 64);
    const float linv = 1.0f / Lt;
    const int s = qt * 256 + wave * 64 + qs * 32 + q31;
    bhalf_t* ob = outp + ((size_t)(b * 2048 + s)) * 1024 + hh * 64;
#pragma unroll
    for (int dd = 0; dd < 2; ++dd)
#pragma unroll
      for (int g = 0; g < 4; ++g) {
        bf16x4 o;
        o.x = (bhalf_t)(Ot[qs][dd][4 * g + 0] * linv);
        o.y = (bhalf_t)(Ot[qs][dd][4 * g + 1] * linv);
        o.z = (bhalf_t)(Ot[qs][dd][4 * g + 2] * linv);
        o.w = (bhalf_t)(Ot[qs][dd][4 * g + 3] * linv);
        *(bf16x4*)(ob + dd * 32 + g * 8 + h * 4) = o;
      }
  }
}

// ---------------------------------------------------------------------------
extern "C" void kernel_launch(void* const* d_in, const int* in_sizes, int n_in,
                              void* d_out, int out_size, void* d_ws, size_t ws_size,
                              hipStream_t stream)
{
  const float* Q  = (const float*)d_in[0];
  const float* K  = (const float*)d_in[1];
  const float* V  = (const float*)d_in[2];
  const float* Wq = (const float*)d_in[3];
  const float* bq = (const float*)d_in[4];
  const float* Wk = (const float*)d_in[5];
  const float* bk = (const float*)d_in[6];
  const float* Wv = (const float*)d_in[7];
  const float* bv = (const float*)d_in[8];
  const float* Wo = (const float*)d_in[9];
  const float* bo = (const float*)d_in[10];

  char* ws = (char*)d_ws;
  const size_t SZ = 8192ull * 1024 * 2;   // 16 MB  [8192,1024] bf16
  const size_t WZ = 1024ull * 1024 * 2;   //  2 MB  [1024,1024] bf16
  bhalf_t* Qb   = (bhalf_t*)(ws);
  bhalf_t* Kb   = (bhalf_t*)(ws + SZ);
  bhalf_t* Vb   = (bhalf_t*)(ws + 2 * SZ);
  bhalf_t* Wqb  = (bhalf_t*)(ws + 3 * SZ);
  bhalf_t* Wkb  = (bhalf_t*)(ws + 3 * SZ + WZ);
  bhalf_t* Wvb  = (bhalf_t*)(ws + 3 * SZ + 2 * WZ);
  bhalf_t* Wob  = (bhalf_t*)(ws + 3 * SZ + 3 * WZ);
  bhalf_t* q_p  = (bhalf_t*)(ws + 3 * SZ + 4 * WZ);
  bhalf_t* k_p  = (bhalf_t*)(ws + 4 * SZ + 4 * WZ);
  bhalf_t* vt_p = (bhalf_t*)(ws + 5 * SZ + 4 * WZ);
  bhalf_t* attn_o = Qb;   // alias: Qb is dead after proj_gemm

  cvt_all<<<28672, 256, 0, stream>>>(Q, K, V, Wq, Wk, Wv, Wo,
                                     Qb, Kb, Vb, Wqb, Wkb, Wvb, Wob);
  proj_gemm<<<1536, 256, 0, stream>>>(Qb, Kb, Vb, Wqb, Wkb, Wvb,
                                      bq, bk, bv, q_p, k_p, vt_p);
  attn_kernel<<<dim3(8, 64), 256, 0, stream>>>(q_p, k_p, vt_p, attn_o);
  out_gemm<<<512, 256, 0, stream>>>(attn_o, Wob, bo, (float*)d_out);
}